// Round 4
// 795.443 us; speedup vs baseline: 1.0270x; 1.0270x over previous
//
#include <hip/hip_runtime.h>
#include <hip/hip_bf16.h>
#include <math.h>

#define MEM_DIM  100
#define TIME_DIM 100
#define EDGE_DIM 172
#define HIDDEN   128
#define IN_DIM   472
#define K_PAD    480          // 15 chunks of 32; rows 472..479 zero
#define NCHUNK   15
#define BM       256          // edges per block (16 waves x 16)
#define THREADS  1024
#define W1_ELEMS (NCHUNK * 8 * 64 * 8)   // 61440 bf16
#define W1_BYTES (W1_ELEMS * 2)          // 122880 B

typedef __attribute__((ext_vector_type(8))) short bf16x8;
typedef __attribute__((ext_vector_type(4))) float floatx4;

typedef const __attribute__((address_space(1))) unsigned int* gp_t;
typedef __attribute__((address_space(3))) unsigned int* lp_t;

// ---------------------------------------------------------------------------
// Prep: permute W1 (fp32, [IN_DIM][HIDDEN]) into bf16 MFMA-B fragment order:
//   value = W1[k][n], k = c*32 + quad*8 + j, n = t*16 + r
//   w1p element offset = ((c*8 + t)*64 + quad*16 + r)*8 + j
// Rows k >= IN_DIM are zeroed (d_ws is 0xAA-poisoned before every call).
// ---------------------------------------------------------------------------
__global__ void prep_w1(const float* __restrict__ w1, __hip_bfloat16* __restrict__ w1p) {
    int idx = blockIdx.x * 256 + threadIdx.x;          // over K_PAD*HIDDEN
    if (idx >= K_PAD * HIDDEN) return;
    int k = idx >> 7;                                  // coalesced read: n fastest
    int n = idx & 127;
    float v = (k < IN_DIM) ? w1[k * HIDDEN + n] : 0.0f;
    int c = k >> 5, kl = k & 31, quad = kl >> 3, j = kl & 7;
    int t = n >> 4, r = n & 15;
    int off = ((c * 8 + t) * 64 + quad * 16 + r) * 8 + j;
    w1p[off] = __float2bfloat16(v);
}

// ---------------------------------------------------------------------------
// Fused TGN decoder, barrier-free main loop:
//   - Whole W1 (frag order, 122880 B) staged to LDS ONCE per block.
//   - X (gather + time-encode) packed directly in registers: thread (edge m,
//     quad q) produces exactly its own A-fragment — no LDS round-trip.
//   - 15 chunks x 8 MFMAs per wave with NO __syncthreads in the loop:
//     16 free-running waves/CU hide the random-gather latency.
//   - Output staged in LDS, stored coalesced (1 KB/block) to kill the
//     partial-line write amplification (41 MB -> ~3 MB).
// ---------------------------------------------------------------------------
__global__ __launch_bounds__(THREADS, 4)
void tgn_mfma(const int* __restrict__ src, const int* __restrict__ dst,
              const float* __restrict__ t, const float* __restrict__ edge_attr,
              const float* __restrict__ memory, const float* __restrict__ last_update,
              const float* __restrict__ time_w, const float* __restrict__ time_b,
              const __hip_bfloat16* __restrict__ w1p, const float* __restrict__ b1,
              const float* __restrict__ w2, const float* __restrict__ b2,
              float* __restrict__ out, int E)
{
    extern __shared__ __hip_bfloat16 W1s[];      // 122880 B dynamic LDS
    __shared__ int   s_src[BM];
    __shared__ int   s_dst[BM];
    __shared__ float s_dt[BM];
    __shared__ float s_tw[TIME_DIM], s_tb[TIME_DIM];
    __shared__ float s_b1[HIDDEN], s_w2[HIDDEN];
    __shared__ float s_out[BM];

    const int tid  = threadIdx.x;
    const int e0   = blockIdx.x * BM;
    const int g    = tid >> 6;          // wave id: edges [g*16, g*16+16)
    const int lane = tid & 63;
    const int quad = (tid >> 4) & 3;
    const int r    = tid & 15;

    // ---- stage ALL of W1 into LDS once: pure 16 B async copies ----
    #pragma unroll
    for (int i = 0; i < 8; ++i) {
        int off = i * (THREADS * 16) + tid * 16;
        if (off < W1_BYTES) {   // last round: tid < 512 (wave-uniform)
            __builtin_amdgcn_global_load_lds(
                (gp_t)(const void*)((const char*)w1p + off),
                (lp_t)(void*)((char*)W1s + off), 16, 0, 0);
        }
    }
    if (tid < BM) {
        int e = e0 + tid; if (e >= E) e = E - 1;   // clamp; store is guarded
        int s = src[e];
        s_src[tid] = s;
        s_dst[tid] = dst[e];
        s_dt[tid]  = t[e] - last_update[s];
    }
    if (tid < HIDDEN) { s_b1[tid] = b1[tid]; s_w2[tid] = w2[tid]; }
    if (tid < TIME_DIM) { s_tw[tid] = time_w[tid]; s_tb[tid] = time_b[tid]; }
    __syncthreads();   // the ONLY barrier before the epilogue

    // per-thread row pointers (thread owns edge m, k-span [c*32+quad*8, +8))
    const int m = g * 16 + r;
    const float* srcrow = memory + (long)s_src[m] * MEM_DIM;
    const float* dstrow = memory + (long)s_dst[m] * MEM_DIM;
    int em = e0 + m; if (em >= E) em = E - 1;
    const float* earow = edge_attr + (long)em * EDGE_DIM;
    const float dt = s_dt[m];

    floatx4 acc[8];
    #pragma unroll
    for (int i = 0; i < 8; ++i) acc[i] = (floatx4){0.f, 0.f, 0.f, 0.f};

    #pragma unroll
    for (int c = 0; c < NCHUNK; ++c) {
        // ---- build X fragment in registers (no LDS, no barrier) ----
        const int kb = c * 32 + quad * 8;
        float v[8];
        if (kb + 7 < MEM_DIM) {
            float4 lo = *(const float4*)(srcrow + kb);
            float4 hi = *(const float4*)(srcrow + kb + 4);
            v[0]=lo.x; v[1]=lo.y; v[2]=lo.z; v[3]=lo.w;
            v[4]=hi.x; v[5]=hi.y; v[6]=hi.z; v[7]=hi.w;
        } else if (kb >= MEM_DIM && kb + 7 < 2 * MEM_DIM) {
            float4 lo = *(const float4*)(dstrow + kb - MEM_DIM);
            float4 hi = *(const float4*)(dstrow + kb - MEM_DIM + 4);
            v[0]=lo.x; v[1]=lo.y; v[2]=lo.z; v[3]=lo.w;
            v[4]=hi.x; v[5]=hi.y; v[6]=hi.z; v[7]=hi.w;
        } else if (kb >= 200 && kb + 7 < 300) {
            int c0 = kb - 200;
            #pragma unroll
            for (int j = 0; j < 8; ++j)
                v[j] = cosf(dt * s_tw[c0 + j] + s_tb[c0 + j]);
        } else if (kb >= 300 && kb + 7 < IN_DIM) {
            float4 lo = *(const float4*)(earow + kb - 300);
            float4 hi = *(const float4*)(earow + kb - 300 + 4);
            v[0]=lo.x; v[1]=lo.y; v[2]=lo.z; v[3]=lo.w;
            v[4]=hi.x; v[5]=hi.y; v[6]=hi.z; v[7]=hi.w;
        } else {
            #pragma unroll
            for (int j = 0; j < 8; ++j) {
                int k = kb + j;
                float x;
                if (k < MEM_DIM)          x = srcrow[k];
                else if (k < 2 * MEM_DIM) x = dstrow[k - MEM_DIM];
                else if (k < 300)         x = cosf(dt * s_tw[k - 200] + s_tb[k - 200]);
                else if (k < IN_DIM)      x = earow[k - 300];
                else                      x = 0.0f;
                v[j] = x;
            }
        }
        bf16x8 af;
        #pragma unroll
        for (int j = 0; j < 8; ++j)
            af[j] = (short)__bfloat16_as_ushort(__float2bfloat16(v[j]));

        // ---- 8 MFMAs: wave g's 16 edges x all 128 cols, K=32 ----
        #pragma unroll
        for (int tnum = 0; tnum < 8; ++tnum) {
            bf16x8 bfrag = ((bf16x8*)W1s)[(c * 8 + tnum) * 64 + lane];
            acc[tnum] = __builtin_amdgcn_mfma_f32_16x16x32_bf16(af, bfrag, acc[tnum], 0, 0, 0);
        }
    }

    // ---- epilogue: h = relu(acc + b1); out = h . w2 + b2 (all fp32) ----
    // C/D layout: n = tnum*16 + (lane&15), m_local = quad*4 + reg
    float part[4] = {0.f, 0.f, 0.f, 0.f};
    #pragma unroll
    for (int tnum = 0; tnum < 8; ++tnum) {
        int n = tnum * 16 + r;
        float b1n = s_b1[n];
        float w2n = s_w2[n];
        #pragma unroll
        for (int reg = 0; reg < 4; ++reg) {
            float h = acc[tnum][reg] + b1n;
            h = h > 0.f ? h : 0.f;
            part[reg] += h * w2n;
        }
    }
    const float b2v = b2[0];
    #pragma unroll
    for (int reg = 0; reg < 4; ++reg) {
        float p = part[reg];
        p += __shfl_xor(p, 1, 64);
        p += __shfl_xor(p, 2, 64);
        p += __shfl_xor(p, 4, 64);
        p += __shfl_xor(p, 8, 64);
        if (r == 0) s_out[g * 16 + quad * 4 + reg] = p + b2v;
    }
    __syncthreads();
    // coalesced 1 KB store per block (kills partial-line write amplification)
    if (tid < BM) {
        int e = e0 + tid;
        if (e < E) out[e] = s_out[tid];
    }
}

extern "C" void kernel_launch(void* const* d_in, const int* in_sizes, int n_in,
                              void* d_out, int out_size, void* d_ws, size_t ws_size,
                              hipStream_t stream) {
    const int*   src = (const int*)d_in[0];
    const int*   dst = (const int*)d_in[1];
    const float* t   = (const float*)d_in[2];
    const float* ea  = (const float*)d_in[3];
    const float* mem = (const float*)d_in[4];
    const float* lu  = (const float*)d_in[5];
    const float* tw  = (const float*)d_in[6];
    const float* tb  = (const float*)d_in[7];
    const float* w1  = (const float*)d_in[8];
    const float* b1  = (const float*)d_in[9];
    const float* w2  = (const float*)d_in[10];
    const float* b2  = (const float*)d_in[11];
    float* out = (float*)d_out;
    const int E = in_sizes[0];

    __hip_bfloat16* w1p = (__hip_bfloat16*)d_ws;   // 480*128*2 = 122880 B

    // allow >64 KB dynamic LDS (host-side, graph-capture-safe; once)
    static bool attr_set = false;
    if (!attr_set) {
        (void)hipFuncSetAttribute(reinterpret_cast<const void*>(tgn_mfma),
                                  hipFuncAttributeMaxDynamicSharedMemorySize,
                                  W1_BYTES);
        attr_set = true;
    }

    prep_w1<<<(K_PAD * HIDDEN + 255) / 256, 256, 0, stream>>>(w1, w1p);

    int grid = (E + BM - 1) / BM;
    tgn_mfma<<<grid, THREADS, W1_BYTES, stream>>>(src, dst, t, ea, mem, lu, tw, tb,
                                                  w1p, b1, w2, b2, out, E);
}

// Round 7
// 792.212 us; speedup vs baseline: 1.0312x; 1.0041x over previous
//
#include <hip/hip_runtime.h>
#include <hip/hip_bf16.h>
#include <math.h>

#define MEM_DIM  100
#define TIME_DIM 100
#define EDGE_DIM 172
#define HIDDEN   128
#define IN_DIM   472
// Re-permuted K: each region padded to a multiple of 32 so every 32-chunk is
// homogeneous (branch-free gather). src[0,128) dst[128,256) time[256,384)
// edge[384,576). MFMA sums over k in any order; prep_w1 applies the same
// permutation to B, so the result is identical.
#define K_PAD    576
#define NCHUNK   18
#define BM       256          // edges per block (16 waves x 16)
#define THREADS  1024
#define W1_ELEMS (NCHUNK * 8 * 64 * 8)   // 73728 bf16
#define W1_BYTES (W1_ELEMS * 2)          // 147456 B

typedef __attribute__((ext_vector_type(8))) short bf16x8;
typedef __attribute__((ext_vector_type(4))) float floatx4;

typedef const __attribute__((address_space(1))) unsigned int* gp_t;
typedef __attribute__((address_space(3))) unsigned int* lp_t;

#define LD4(p) (*(const float4*)(p))

// ---------------------------------------------------------------------------
// Prep: permute W1 (fp32, [IN_DIM][HIDDEN]) into bf16 MFMA-B fragment order
// under the padded-region k' mapping:
//   k' < 128  -> k = k'        (valid k' < 100)         src
//   k' < 256  -> k = 100+k'-128 (valid k'-128 < 100)    dst
//   k' < 384  -> k = 200+k'-256 (valid k'-256 < 100)    time
//   else      -> k = 300+k'-384 (valid k'-384 < 172)    edge
// frag offset: c=k'>>5, quad=(k'&31)>>3, j=k'&7, t=n>>4, r=n&15
//   off = ((c*8 + t)*64 + quad*16 + r)*8 + j
// ---------------------------------------------------------------------------
__global__ void prep_w1(const float* __restrict__ w1, __hip_bfloat16* __restrict__ w1p) {
    int idx = blockIdx.x * 256 + threadIdx.x;          // over K_PAD*HIDDEN
    if (idx >= K_PAD * HIDDEN) return;
    int kp = idx >> 7;
    int n  = idx & 127;
    int k; bool valid;
    if (kp < 128)      { k = kp;              valid = kp < 100; }
    else if (kp < 256) { k = 100 + kp - 128;  valid = (kp - 128) < 100; }
    else if (kp < 384) { k = 200 + kp - 256;  valid = (kp - 256) < 100; }
    else               { k = 300 + kp - 384;  valid = (kp - 384) < 172; }
    float v = valid ? w1[k * HIDDEN + n] : 0.0f;
    int c = kp >> 5, kl = kp & 31, quad = kl >> 3, j = kl & 7;
    int t = n >> 4, r = n & 15;
    int off = ((c * 8 + t) * 64 + quad * 16 + r) * 8 + j;
    w1p[off] = __float2bfloat16(v);
}

// ---------------------------------------------------------------------------
// Fused TGN decoder. Barrier-free main body, branch-free gathers:
//   - whole W1 (147456 B, frag order) in LDS once per block
//   - per-thread X fragments built in registers; loads batched region-by-
//     region so ~14 gathers are in flight before the first vmcnt wait;
//     the 4 cos chunks (pure VALU) run right after load issue to cover
//     the HBM/L3 gather latency.
// ---------------------------------------------------------------------------
__global__ __launch_bounds__(THREADS, 4)
void tgn_mfma(const int* __restrict__ src, const int* __restrict__ dst,
              const float* __restrict__ t, const float* __restrict__ edge_attr,
              const float* __restrict__ memory, const float* __restrict__ last_update,
              const float* __restrict__ time_w, const float* __restrict__ time_b,
              const __hip_bfloat16* __restrict__ w1p, const float* __restrict__ b1,
              const float* __restrict__ w2, const float* __restrict__ b2,
              float* __restrict__ out, int E)
{
    extern __shared__ __hip_bfloat16 W1s[];      // 147456 B dynamic LDS
    __shared__ int   s_src[BM];
    __shared__ int   s_dst[BM];
    __shared__ float s_dt[BM];
    __shared__ float s_tw[TIME_DIM], s_tb[TIME_DIM];
    __shared__ float s_b1[HIDDEN], s_w2[HIDDEN];
    __shared__ float s_out[BM];

    const int tid  = threadIdx.x;
    const int e0   = blockIdx.x * BM;
    const int g    = tid >> 6;          // wave id: edges [g*16, g*16+16)
    const int lane = tid & 63;
    const int quad = (tid >> 4) & 3;
    const int r    = tid & 15;

    // ---- stage ALL of W1 into LDS once: 9 x (1024 lanes x 16 B) ----
    #pragma unroll
    for (int i = 0; i < 9; ++i) {
        int off = i * (THREADS * 16) + tid * 16;   // 9*16384 == 147456 exactly
        __builtin_amdgcn_global_load_lds(
            (gp_t)(const void*)((const char*)w1p + off),
            (lp_t)(void*)((char*)W1s + off), 16, 0, 0);
    }
    if (tid < BM) {
        int e = e0 + tid; if (e >= E) e = E - 1;   // clamp; store is guarded
        int s = src[e];
        s_src[tid] = s;
        s_dst[tid] = dst[e];
        s_dt[tid]  = t[e] - last_update[s];
    }
    if (tid < HIDDEN) { s_b1[tid] = b1[tid]; s_w2[tid] = w2[tid]; }
    if (tid < TIME_DIM) { s_tw[tid] = time_w[tid]; s_tb[tid] = time_b[tid]; }
    __syncthreads();   // the ONLY barrier before the epilogue

    const int m = g * 16 + r;
    const float* srcrow = memory + (long)s_src[m] * MEM_DIM;
    const float* dstrow = memory + (long)s_dst[m] * MEM_DIM;
    int em = e0 + m; if (em >= E) em = E - 1;
    const float* earow = edge_attr + (long)em * EDGE_DIM;
    const float dt = s_dt[m];
    const int qo = quad * 8;

    floatx4 acc[8];
    #pragma unroll
    for (int i = 0; i < 8; ++i) acc[i] = (floatx4){0.f, 0.f, 0.f, 0.f};

    // one chunk = pack 8 floats -> bf16 A-frag, 8 MFMAs against LDS B-frags
    auto do_chunk = [&](int c, const float* v) {
        bf16x8 af;
        #pragma unroll
        for (int j = 0; j < 8; ++j)
            af[j] = (short)__bfloat16_as_ushort(__float2bfloat16(v[j]));
        #pragma unroll
        for (int tnum = 0; tnum < 8; ++tnum) {
            bf16x8 bfrag = ((bf16x8*)W1s)[(c * 8 + tnum) * 64 + lane];
            acc[tnum] = __builtin_amdgcn_mfma_f32_16x16x32_bf16(af, bfrag, acc[tnum], 0, 0, 0);
        }
    };

    // ================= batch 1: issue ALL src + dst gathers (14 float4) ====
    float4 s0a = LD4(srcrow + qo);       float4 s0b = LD4(srcrow + qo + 4);
    float4 s1a = LD4(srcrow + 32 + qo);  float4 s1b = LD4(srcrow + 36 + qo);
    float4 s2a = LD4(srcrow + 64 + qo);  float4 s2b = LD4(srcrow + 68 + qo);
    float4 s3  = LD4(srcrow + 96);       // uniform addr; valid for quad==0 only
    float4 d0a = LD4(dstrow + qo);       float4 d0b = LD4(dstrow + qo + 4);
    float4 d1a = LD4(dstrow + 32 + qo);  float4 d1b = LD4(dstrow + 36 + qo);
    float4 d2a = LD4(dstrow + 64 + qo);  float4 d2b = LD4(dstrow + 68 + qo);
    float4 d3  = LD4(dstrow + 96);       // uniform addr; valid for quad==0 only

    // ========== time chunks 8..11 first: pure VALU, covers gather latency ==
    #pragma unroll
    for (int c = 8; c < 11; ++c) {
        int i0 = (c - 8) * 32 + qo;
        float v[8];
        #pragma unroll
        for (int j = 0; j < 8; ++j)
            v[j] = cosf(dt * s_tw[i0 + j] + s_tb[i0 + j]);
        do_chunk(c, v);
    }
    {   // c=11 boundary: time[96..99] for quad==0 lanes, rest zero
        bool p0 = (quad == 0);
        float v[8];
        #pragma unroll
        for (int j = 0; j < 4; ++j) {
            float cv = cosf(dt * s_tw[96 + j] + s_tb[96 + j]);
            v[j] = p0 ? cv : 0.f;
        }
        v[4] = v[5] = v[6] = v[7] = 0.f;
        do_chunk(11, v);
    }

    // ================= src chunks 0..3 =====================================
    {
        float v[8] = {s0a.x,s0a.y,s0a.z,s0a.w, s0b.x,s0b.y,s0b.z,s0b.w};
        do_chunk(0, v);
    }
    {
        float v[8] = {s1a.x,s1a.y,s1a.z,s1a.w, s1b.x,s1b.y,s1b.z,s1b.w};
        do_chunk(1, v);
    }
    {
        float v[8] = {s2a.x,s2a.y,s2a.z,s2a.w, s2b.x,s2b.y,s2b.z,s2b.w};
        do_chunk(2, v);
    }
    {   // boundary: src[96..99] for quad==0, rest zero
        bool p0 = (quad == 0);
        float v[8] = {p0?s3.x:0.f, p0?s3.y:0.f, p0?s3.z:0.f, p0?s3.w:0.f,
                      0.f, 0.f, 0.f, 0.f};
        do_chunk(3, v);
    }

    // ============ batch 2: issue ALL edge gathers (12 float4) ==============
    float4 e0a = LD4(earow + qo);        float4 e0b = LD4(earow + qo + 4);
    float4 e1a = LD4(earow + 32 + qo);   float4 e1b = LD4(earow + 36 + qo);
    float4 e2a = LD4(earow + 64 + qo);   float4 e2b = LD4(earow + 68 + qo);
    float4 e3a = LD4(earow + 96 + qo);   float4 e3b = LD4(earow + 100 + qo);
    float4 e4a = LD4(earow + 128 + qo);  float4 e4b = LD4(earow + 132 + qo);
    // c=17 boundary: quad0 -> [160..167], quad1 -> [168..171], quad2/3 -> 0
    float4 e5a = LD4(earow + ((quad <= 1) ? 160 + qo : 160));  // safe aligned
    float4 e5b = LD4(earow + ((quad == 0) ? 164 : 160));       // safe aligned

    // ================= dst chunks 4..7 =====================================
    {
        float v[8] = {d0a.x,d0a.y,d0a.z,d0a.w, d0b.x,d0b.y,d0b.z,d0b.w};
        do_chunk(4, v);
    }
    {
        float v[8] = {d1a.x,d1a.y,d1a.z,d1a.w, d1b.x,d1b.y,d1b.z,d1b.w};
        do_chunk(5, v);
    }
    {
        float v[8] = {d2a.x,d2a.y,d2a.z,d2a.w, d2b.x,d2b.y,d2b.z,d2b.w};
        do_chunk(6, v);
    }
    {   // boundary: dst[96..99] for quad==0, rest zero
        bool p0 = (quad == 0);
        float v[8] = {p0?d3.x:0.f, p0?d3.y:0.f, p0?d3.z:0.f, p0?d3.w:0.f,
                      0.f, 0.f, 0.f, 0.f};
        do_chunk(7, v);
    }

    // ================= edge chunks 12..17 ==================================
    {
        float v[8] = {e0a.x,e0a.y,e0a.z,e0a.w, e0b.x,e0b.y,e0b.z,e0b.w};
        do_chunk(12, v);
    }
    {
        float v[8] = {e1a.x,e1a.y,e1a.z,e1a.w, e1b.x,e1b.y,e1b.z,e1b.w};
        do_chunk(13, v);
    }
    {
        float v[8] = {e2a.x,e2a.y,e2a.z,e2a.w, e2b.x,e2b.y,e2b.z,e2b.w};
        do_chunk(14, v);
    }
    {
        float v[8] = {e3a.x,e3a.y,e3a.z,e3a.w, e3b.x,e3b.y,e3b.z,e3b.w};
        do_chunk(15, v);
    }
    {
        float v[8] = {e4a.x,e4a.y,e4a.z,e4a.w, e4b.x,e4b.y,e4b.z,e4b.w};
        do_chunk(16, v);
    }
    {   // boundary c=17: q0 full 8, q1 first 4, q2/q3 zero
        bool pA = (quad <= 1);
        bool pB = (quad == 0);
        float v[8] = {pA?e5a.x:0.f, pA?e5a.y:0.f, pA?e5a.z:0.f, pA?e5a.w:0.f,
                      pB?e5b.x:0.f, pB?e5b.y:0.f, pB?e5b.z:0.f, pB?e5b.w:0.f};
        do_chunk(17, v);
    }

    // ---- epilogue: h = relu(acc + b1); out = h . w2 + b2 (all fp32) ----
    // C/D layout: n = tnum*16 + (lane&15), m_local = quad*4 + reg
    float part[4] = {0.f, 0.f, 0.f, 0.f};
    #pragma unroll
    for (int tnum = 0; tnum < 8; ++tnum) {
        int n = tnum * 16 + r;
        float b1n = s_b1[n];
        float w2n = s_w2[n];
        #pragma unroll
        for (int reg = 0; reg < 4; ++reg) {
            float h = acc[tnum][reg] + b1n;
            h = h > 0.f ? h : 0.f;
            part[reg] += h * w2n;
        }
    }
    const float b2v = b2[0];
    #pragma unroll
    for (int reg = 0; reg < 4; ++reg) {
        float p = part[reg];
        p += __shfl_xor(p, 1, 64);
        p += __shfl_xor(p, 2, 64);
        p += __shfl_xor(p, 4, 64);
        p += __shfl_xor(p, 8, 64);
        if (r == 0) s_out[g * 16 + quad * 4 + reg] = p + b2v;
    }
    __syncthreads();
    // coalesced 1 KB store per block
    if (tid < BM) {
        int e = e0 + tid;
        if (e < E) out[e] = s_out[tid];
    }
}

extern "C" void kernel_launch(void* const* d_in, const int* in_sizes, int n_in,
                              void* d_out, int out_size, void* d_ws, size_t ws_size,
                              hipStream_t stream) {
    const int*   src = (const int*)d_in[0];
    const int*   dst = (const int*)d_in[1];
    const float* t   = (const float*)d_in[2];
    const float* ea  = (const float*)d_in[3];
    const float* mem = (const float*)d_in[4];
    const float* lu  = (const float*)d_in[5];
    const float* tw  = (const float*)d_in[6];
    const float* tb  = (const float*)d_in[7];
    const float* w1  = (const float*)d_in[8];
    const float* b1  = (const float*)d_in[9];
    const float* w2  = (const float*)d_in[10];
    const float* b2  = (const float*)d_in[11];
    float* out = (float*)d_out;
    const int E = in_sizes[0];

    __hip_bfloat16* w1p = (__hip_bfloat16*)d_ws;   // 576*128*2 = 147456 B

    // allow >64 KB dynamic LDS (host-side, graph-capture-safe; once)
    static bool attr_set = false;
    if (!attr_set) {
        (void)hipFuncSetAttribute(reinterpret_cast<const void*>(tgn_mfma),
                                  hipFuncAttributeMaxDynamicSharedMemorySize,
                                  W1_BYTES);
        attr_set = true;
    }

    prep_w1<<<(K_PAD * HIDDEN + 255) / 256, 256, 0, stream>>>(w1, w1p);

    int grid = (E + BM - 1) / BM;
    tgn_mfma<<<grid, THREADS, W1_BYTES, stream>>>(src, dst, t, ea, mem, lu, tw, tb,
                                                  w1p, b1, w2, b2, out, E);
}